// Round 5
// baseline (657.124 us; speedup 1.0000x reference)
//
#include <hip/hip_runtime.h>
#include <stdint.h>

// PackBits: out[w] = packed sign bits of x[32w .. 32w+31].
// Bit mapping (np.packbits MSB-first + little-endian uint32 view):
//   element p -> bit q = 8*(p>>3) + 7 - (p&7)
// Natural-order word nat (bit t = signbit(x[32w+t])), then
//   out = bswap(brev(nat))   — verified correct (absmax 0) in all rounds.
//
// R7 = best-of(R5, R6): discriminating experiment.
//  - Load side from R5 (646 us, best): 8x nontemporal dwordx4 per wave,
//    contiguous 32 KiB block tile, 16384 blocks. (R6's 32x dword loads: 655.)
//  - Pack/store side from R6: __ballot replaces the 3-step ds_swizzle
//    butterfly (24 LDS-pipe ops/wave in R5) and the 1/8-exec-masked 32 B
//    stores; one fully-coalesced 256 B NT store per wave.
//  - New piece: dwordx4 loads put 4 consecutive floats per lane, so the 4
//    per-component ballots give sign masks at stride 4. Per round, each lane
//    captures byte (lane&7) of each ballot; after 8 rounds one 4-way
//    bit-interleave (mask/shift spread, 9 ops/byte) rebuilds the natural
//    word for this lane's output index, then bswap(brev(.)).
// If this lands ~646-650 (no change), the kernel is at its HBM floor and
// dur_us is dominated by fixed harness re-poison traffic -> roofline.

typedef uint32_t u32;
typedef unsigned long long u64;
typedef int ivec4 __attribute__((ext_vector_type(4)));

#define THREADS 256
#define ROUNDS  8
#define WAVE_FLOATS  (ROUNDS * 256)      // 2048 floats per wave (8 KiB)
#define BLOCK_FLOATS (4 * WAVE_FLOATS)   // 8192 floats per block (32 KiB)

__device__ __forceinline__ u32 interleave4(u32 cap) {
  // nat bit (4k+c) = bit k of byte c of cap
  u32 nat = 0;
#pragma unroll
  for (int c = 0; c < 4; ++c) {
    u32 b = (cap >> (8 * c)) & 0xffu;
    b = (b | (b << 12)) & 0x000F000Fu;
    b = (b | (b << 6))  & 0x03030303u;
    b = (b | (b << 3))  & 0x11111111u;
    nat |= b << c;
  }
  return nat;
}

__global__ __launch_bounds__(THREADS) void PackBits_61289183314094_kernel(
    const ivec4* __restrict__ x4, u32* __restrict__ out, int n) {
  const int wave = threadIdx.x >> 6;
  const int lane = threadIdx.x & 63;
  const int fbase = blockIdx.x * BLOCK_FLOATS + wave * WAVE_FLOATS;  // uniform
  const int sh = 8 * (lane & 7);   // byte slot within each ballot
  const int myj = lane >> 3;       // which round this lane's word comes from

  if (fbase + WAVE_FLOATS <= n) {
    const ivec4* p = x4 + (fbase >> 2) + lane;
    ivec4 v[ROUNDS];
#pragma unroll
    for (int j = 0; j < ROUNDS; ++j)
      v[j] = __builtin_nontemporal_load(&p[j * 64]);

    u32 cap = 0;
#pragma unroll
    for (int j = 0; j < ROUNDS; ++j) {
      // ballot b_c bit i = signbit(x[fbase + 256j + 4i + c])
      u64 b0 = __ballot(v[j].x < 0);
      u64 b1 = __ballot(v[j].y < 0);
      u64 b2 = __ballot(v[j].z < 0);
      u64 b3 = __ballot(v[j].w < 0);
      u32 t = ((u32)(b0 >> sh) & 0xffu)
            | (((u32)(b1 >> sh) & 0xffu) << 8)
            | (((u32)(b2 >> sh) & 0xffu) << 16)
            | (((u32)(b3 >> sh) & 0xffu) << 24);
      cap = (myj == j) ? t : cap;
    }
    // lane L owns global word fbase/32 + L, covering floats fbase+32L..+31;
    // cap byte c bit k = sign(float fbase + 256*myj + 32*(lane&7) + 4k + c)
    u32 w = __builtin_bswap32(__brev(interleave4(cap)));
    __builtin_nontemporal_store(w, &out[(fbase >> 5) + lane]);
  } else {
    // Tail (unused for N = 2^27; kept general). Wave-uniform branch: all 64
    // lanes join every ballot. Reference zero-pads; signbit(0) = 0.
    const int nwords = (n + 31) >> 5;
    const int* xs = (const int*)x4;
    u32 cap = 0;
    for (int j = 0; j < ROUNDS; ++j) {
      u64 b[4];
      for (int c = 0; c < 4; ++c) {
        int idx = fbase + j * 256 + 4 * lane + c;
        int val = (idx < n) ? xs[idx] : 0;
        b[c] = __ballot(val < 0);
      }
      u32 t = ((u32)(b[0] >> sh) & 0xffu)
            | (((u32)(b[1] >> sh) & 0xffu) << 8)
            | (((u32)(b[2] >> sh) & 0xffu) << 16)
            | (((u32)(b[3] >> sh) & 0xffu) << 24);
      cap = (myj == j) ? t : cap;
    }
    int wi = (fbase >> 5) + lane;
    if (wi < nwords) out[wi] = __builtin_bswap32(__brev(interleave4(cap)));
  }
}

extern "C" void kernel_launch(void* const* d_in, const int* in_sizes, int n_in,
                              void* d_out, int out_size, void* d_ws, size_t ws_size,
                              hipStream_t stream) {
  const ivec4* x4 = (const ivec4*)d_in[0];
  u32* out = (u32*)d_out;
  int n = in_sizes[0];  // 2^27 floats

  int blocks = (n + BLOCK_FLOATS - 1) / BLOCK_FLOATS;  // 16384 for N = 2^27
  PackBits_61289183314094_kernel<<<blocks, THREADS, 0, stream>>>(x4, out, n);
}